// Round 2
// baseline (167.258 us; speedup 1.0000x reference)
//
#include <hip/hip_runtime.h>

#define BB 256
#define LL 512
#define TT 128
#define CH 16  // staged steps per chunk

typedef _Float16 h2 __attribute__((ext_vector_type(2)));

static __device__ inline h2 pkrtz(float a, float b) {
  return __builtin_bit_cast(h2, __builtin_amdgcn_cvt_pkrtz(a, b));
}

#if defined(__has_builtin)
#if __has_builtin(__builtin_amdgcn_fdot2)
#define FDOT2(a, b, c) __builtin_amdgcn_fdot2((a), (b), (c), false)
#endif
#endif
#ifndef FDOT2
static __device__ inline float fdot2_fb(h2 a, h2 b, float c) {
  return fmaf((float)a.x, (float)b.x, fmaf((float)a.y, (float)b.y, c));
}
#define FDOT2(a, b, c) fdot2_fb((a), (b), (c))
#endif

// Full-wave max via DPP (VALU pipe only — off the LDS queue).
static __device__ inline float wave_max_dpp(float x) {
  int v = __float_as_int(x);
#define DPP_STEP(ctrl)                                                  \
  {                                                                     \
    int t = __builtin_amdgcn_update_dpp(v, v, (ctrl), 0xf, 0xf, false); \
    x = fmaxf(x, __int_as_float(t));                                    \
    v = __float_as_int(x);                                              \
  }
  DPP_STEP(0x111) DPP_STEP(0x112) DPP_STEP(0x114) DPP_STEP(0x118)
  DPP_STEP(0x142) DPP_STEP(0x143)
#undef DPP_STEP
  return __int_as_float(__builtin_amdgcn_readlane(v, 63));
}

static __device__ inline h2 bch2(unsigned u) { return __builtin_bit_cast(h2, u); }
static __device__ inline unsigned expbits(unsigned u) {
  return __float_as_uint(__expf(__uint_as_float(u)));
}

// Round-0 structure (2 independent chain waves + 2 stager waves, barrier
// only per 16-step chunk), but the per-step state broadcast goes through
// v_readlane -> wave-uniform (SGPR) operands of v_dot2 instead of an LDS
// write->read round-trip. The chain loops issue ZERO LDS state ops; the
// only per-step LDS op is one ds_read_b64 of the staged (exp-folded)
// emission, which feeds the final multiply (off the critical path).
// Scale = exact pow2 bookkeeping, identical arithmetic to the verified
// round-0 kernel (exp folded at staging time produces bit-identical f32).
__global__ __launch_bounds__(256)
__attribute__((amdgpu_waves_per_eu(1, 1)))
void crf_fb_kernel(const float* __restrict__ inputs,
                   const float* __restrict__ trans,
                   const float* __restrict__ start_t,
                   const float* __restrict__ end_t,
                   const int* __restrict__ tags,
                   const int* __restrict__ mask,
                   float* __restrict__ diff) {
  const int b = blockIdx.x;
  const int tid = threadIdx.x;
  const int lane = tid & 63;
  const int wid = tid >> 6;

  __shared__ __align__(16) float fbuf[2][CH * TT];  // fwd emissions, exp-folded
  __shared__ __align__(16) float bbuf[2][CH * TT];  // bwd emissions, exp-folded
  __shared__ __align__(16) h2 g_lds[64];            // bwd final state (epilogue)
  __shared__ float numA_sh, numB_sh;
  __shared__ int sb_sh;

  // ---- each wave computes len ----
  int lm = 0;
  const int* mk = mask + b * LL;
#pragma unroll
  for (int q = 0; q < LL / 64; ++q) lm += mk[q * 64 + lane];
#pragma unroll
  for (int d = 1; d < 64; d <<= 1) lm += __shfl_xor(lm, d);
  const int len = lm;            // [256, 512]
  const int m = (len - 1) >> 1;  // meeting point; m >= 127
  const int NC = (len - 1 - m + CH - 1) / CH;  // chunks (bwd has max steps)

  const float* erow = inputs + (size_t)b * LL * TT;
  const float2* er2 = (const float2*)erow;
  const float2* tr2 = (const float2*)trans;

  // stage 16 rows (8 KB), folding exp() so the chain never computes it
  auto STAGE = [&](float* dst, const float* gbase) {
    const uint4* gs = (const uint4*)gbase;
    uint4* ds = (uint4*)dst;
    uint4 v[8];
#pragma unroll
    for (int q = 0; q < 8; ++q) v[q] = gs[q * 64 + lane];
#pragma unroll
    for (int q = 0; q < 8; ++q) {
      uint4 o;
      o.x = expbits(v[q].x);
      o.y = expbits(v[q].y);
      o.z = expbits(v[q].z);
      o.w = expbits(v[q].w);
      ds[q * 64 + lane] = o;
    }
  };

  int S = 0;
  float inv_sc = 1.0f;
  int cur_ex = 0;
  h2 Ea0[64], Ea1[64];  // E fragments (fwd: col-pairs; bwd: row-pairs)
  unsigned sst[64];     // wave-uniform state pairs (readlane-broadcast)
  h2 pk;                // this lane's state pair (outputs 2*lane, 2*lane+1)

  // ================= prologue =================
  if (wid == 0) {
#pragma unroll
    for (int p = 0; p < 64; ++p) {
      float2 r0 = tr2[(2 * p) * 64 + lane];      // row 2p, cols j0,j1
      float2 r1 = tr2[(2 * p + 1) * 64 + lane];  // row 2p+1
      h2 c0, c1;
      c0.x = (_Float16)__expf(r0.x);
      c0.y = (_Float16)__expf(r1.x);
      c1.x = (_Float16)__expf(r0.y);
      c1.y = (_Float16)__expf(r1.y);
      Ea0[p] = c0;
      Ea1[p] = c1;
    }
    float2 em0 = er2[lane];
    float f0 = __expf(start_t[2 * lane] + em0.x);
    float f1 = __expf(start_t[2 * lane + 1] + em0.y);
    pk = pkrtz(f0, f1);
    int pki = (int)__builtin_bit_cast(unsigned, pk);
#pragma unroll
    for (int r = 0; r < 64; ++r)
      sst[r] = (unsigned)__builtin_amdgcn_readlane(pki, r);
    float mx = wave_max_dpp(fmaxf(f0, f1));
    int exm = (int)((__float_as_uint(mx) >> 23) & 255) - 127;
    inv_sc = __uint_as_float((unsigned)(120 - exm) << 23);
    cur_ex = exm + 7;
  } else if (wid == 1) {
#pragma unroll
    for (int p = 0; p < 64; ++p) {
      float2 r0 = tr2[(2 * lane) * 64 + p];
      float2 r1 = tr2[(2 * lane + 1) * 64 + p];
      h2 c0, c1;
      c0.x = (_Float16)__expf(r0.x);
      c0.y = (_Float16)__expf(r0.y);
      c1.x = (_Float16)__expf(r1.x);
      c1.y = (_Float16)__expf(r1.y);
      Ea0[p] = c0;
      Ea1[p] = c1;
    }
    float2 em = er2[(size_t)(len - 1) * 64 + lane];
    float g0 = __expf(end_t[2 * lane] + em.x);
    float g1 = __expf(end_t[2 * lane + 1] + em.y);
    pk = pkrtz(g0, g1);
    int pki = (int)__builtin_bit_cast(unsigned, pk);
#pragma unroll
    for (int r = 0; r < 64; ++r)
      sst[r] = (unsigned)__builtin_amdgcn_readlane(pki, r);
    float mx = wave_max_dpp(fmaxf(g0, g1));
    int exm = (int)((__float_as_uint(mx) >> 23) & 255) - 127;
    inv_sc = __uint_as_float((unsigned)(120 - exm) << 23);
    cur_ex = exm + 7;
  } else if (wid == 2) {
    STAGE(fbuf[0], erow + 1 * TT);  // fwd chunk 0: rows 1..16
    // numerator half A: t in [0, len/2)
    const int* tg = tags + (size_t)b * LL;
    const int hl = len >> 1;
    float sc = 0.f;
    for (int t = lane; t < hl; t += 64) {
      int cu = tg[t];
      sc += erow[(size_t)t * TT + cu];
      if (t >= 1) sc += trans[tg[t - 1] * TT + cu];
    }
    if (lane == 0) sc += start_t[tg[0]];
#pragma unroll
    for (int d = 1; d < 64; d <<= 1) sc += __shfl_xor(sc, d);
    if (lane == 0) numA_sh = sc;
  } else {
    STAGE(bbuf[0], erow + (size_t)(len - 1 - CH) * TT);  // bwd chunk 0
    // numerator half B: t in [len/2, len)
    const int* tg = tags + (size_t)b * LL;
    const int hl = len >> 1;
    float sc = 0.f;
    for (int t = hl + lane; t < len; t += 64) {
      int cu = tg[t];
      sc += erow[(size_t)t * TT + cu];
      sc += trans[tg[t - 1] * TT + cu];
    }
    if (lane == 0) sc += end_t[tg[len - 1]];
#pragma unroll
    for (int d = 1; d < 64; d <<= 1) sc += __shfl_xor(sc, d);
    if (lane == 0) numB_sh = sc;
  }

  __syncthreads();

  // ================= chunk loop =================
  for (int c = 0; c < NC; ++c) {
    if (wid == 0) {
      // ---- forward chain steps of chunk c ----
      const float2* emb = (const float2*)fbuf[c & 1];
      const int tbeg = 1 + CH * c;
      const int tend = min(tbeg + CH - 1, m);
#pragma unroll 1
      for (int t = tbeg; t <= tend; ++t) {
        float2 fe = emb[(t - tbeg) * 64 + lane];  // exp already folded
        float f0 = fe.x * inv_sc;
        float f1 = fe.y * inv_sc;
        float a0 = 0.f, a1 = 0.f, a2 = 0.f, a3 = 0.f;
        float c0 = 0.f, c1 = 0.f, c2 = 0.f, c3 = 0.f;
#pragma unroll
        for (int q = 0; q < 16; ++q) {
          h2 s0 = bch2(sst[4 * q + 0]);
          h2 s1 = bch2(sst[4 * q + 1]);
          h2 s2 = bch2(sst[4 * q + 2]);
          h2 s3 = bch2(sst[4 * q + 3]);
          a0 = FDOT2(s0, Ea0[4 * q + 0], a0);
          a1 = FDOT2(s1, Ea0[4 * q + 1], a1);
          a2 = FDOT2(s2, Ea0[4 * q + 2], a2);
          a3 = FDOT2(s3, Ea0[4 * q + 3], a3);
          c0 = FDOT2(s0, Ea1[4 * q + 0], c0);
          c1 = FDOT2(s1, Ea1[4 * q + 1], c1);
          c2 = FDOT2(s2, Ea1[4 * q + 2], c2);
          c3 = FDOT2(s3, Ea1[4 * q + 3], c3);
        }
        float w0 = ((a0 + a1) + (a2 + a3)) * f0;
        float w1 = ((c0 + c1) + (c2 + c3)) * f1;
        pk = pkrtz(w0, w1);
        int pki = (int)__builtin_bit_cast(unsigned, pk);
#pragma unroll
        for (int r = 0; r < 64; ++r)
          sst[r] = (unsigned)__builtin_amdgcn_readlane(pki, r);
        S += cur_ex;
        float mx = wave_max_dpp(fmaxf(w0, w1));
        int exm = (int)((__float_as_uint(mx) >> 23) & 255) - 127;
        inv_sc = __uint_as_float((unsigned)(120 - exm) << 23);
        cur_ex = exm + 7;
      }
    } else if (wid == 1) {
      // ---- backward chain steps of chunk c ----
      const int thi = len - 2 - CH * c;
      const int lb = len - 1 - CH * (c + 1);  // staged base row
      const int tlo = max(m, lb);
      const float2* emb = (const float2*)bbuf[c & 1];
#pragma unroll 1
      for (int t = thi; t >= tlo; --t) {
        float2 pe = emb[(t - lb) * 64 + lane];  // exp already folded
        float a0 = 0.f, a1 = 0.f, a2 = 0.f, a3 = 0.f;
        float c0 = 0.f, c1 = 0.f, c2 = 0.f, c3 = 0.f;
#pragma unroll
        for (int q = 0; q < 16; ++q) {
          h2 s0 = bch2(sst[4 * q + 0]);
          h2 s1 = bch2(sst[4 * q + 1]);
          h2 s2 = bch2(sst[4 * q + 2]);
          h2 s3 = bch2(sst[4 * q + 3]);
          a0 = FDOT2(s0, Ea0[4 * q + 0], a0);
          a1 = FDOT2(s1, Ea0[4 * q + 1], a1);
          a2 = FDOT2(s2, Ea0[4 * q + 2], a2);
          a3 = FDOT2(s3, Ea0[4 * q + 3], a3);
          c0 = FDOT2(s0, Ea1[4 * q + 0], c0);
          c1 = FDOT2(s1, Ea1[4 * q + 1], c1);
          c2 = FDOT2(s2, Ea1[4 * q + 2], c2);
          c3 = FDOT2(s3, Ea1[4 * q + 3], c3);
        }
        float v0 = (a0 + a1) + (a2 + a3);
        float v1 = (c0 + c1) + (c2 + c3);
        if (t > m) {  // fold exp(emit_t); at t==m store raw
          v0 *= pe.x;
          v1 *= pe.y;
        }
        float w0 = v0 * inv_sc, w1 = v1 * inv_sc;
        pk = pkrtz(w0, w1);
        int pki = (int)__builtin_bit_cast(unsigned, pk);
#pragma unroll
        for (int r = 0; r < 64; ++r)
          sst[r] = (unsigned)__builtin_amdgcn_readlane(pki, r);
        S += cur_ex;
        float mx = wave_max_dpp(fmaxf(w0, w1));
        int exm = (int)((__float_as_uint(mx) >> 23) & 255) - 127;
        inv_sc = __uint_as_float((unsigned)(120 - exm) << 23);
        cur_ex = exm + 7;
      }
    } else if (wid == 2) {
      if (c + 1 < NC) STAGE(fbuf[(c + 1) & 1], erow + (size_t)(1 + CH * (c + 1)) * TT);
    } else {
      if (c + 1 < NC) STAGE(bbuf[(c + 1) & 1], erow + (size_t)(len - 1 - CH * (c + 2)) * TT);
    }
    __syncthreads();
  }

  if (wid == 1) {
    g_lds[lane] = pk;
    if (lane == 0) sb_sh = S;
  }
  __syncthreads();

  if (wid == 0) {
    h2 a = pk;  // final fwd state lives in this wave's registers
    h2 g = g_lds[lane];
    float v = (float)a.x * (float)g.x + (float)a.y * (float)g.y;
#pragma unroll
    for (int d = 1; d < 64; d <<= 1) v += __shfl_xor(v, d);
    if (lane == 0) {
      float log_den = (float)(S + sb_sh) * 0.6931471805599453f + __logf(v);
      diff[b] = (numA_sh + numB_sh) - log_den;
    }
  }
}

// Deterministic final reduction over batch.
__global__ void crf_sum_kernel(const float* __restrict__ diff,
                               float* __restrict__ out) {
  const int tid = threadIdx.x;  // 256
  float v = diff[tid];
#pragma unroll
  for (int d = 1; d < 64; d <<= 1) v += __shfl_xor(v, d);
  __shared__ float r[4];
  if ((tid & 63) == 0) r[tid >> 6] = v;
  __syncthreads();
  if (tid == 0) out[0] = r[0] + r[1] + r[2] + r[3];
}

extern "C" void kernel_launch(void* const* d_in, const int* in_sizes, int n_in,
                              void* d_out, int out_size, void* d_ws, size_t ws_size,
                              hipStream_t stream) {
  const float* inputs = (const float*)d_in[0];
  const float* trans = (const float*)d_in[1];
  const float* start_t = (const float*)d_in[2];
  const float* end_t = (const float*)d_in[3];
  const int* tags = (const int*)d_in[4];
  const int* mask = (const int*)d_in[5];
  float* diff = (float*)d_ws;  // 256 floats
  float* out = (float*)d_out;

  crf_fb_kernel<<<BB, 256, 0, stream>>>(inputs, trans, start_t, end_t, tags,
                                        mask, diff);
  crf_sum_kernel<<<1, 256, 0, stream>>>(diff, out);
}

// Round 3
// 135.296 us; speedup vs baseline: 1.2362x; 1.2362x over previous
//
#include <hip/hip_runtime.h>

#define BB 256
#define LL 512
#define TT 128
#define CH 16  // staged steps per chunk

typedef _Float16 h2 __attribute__((ext_vector_type(2)));

static __device__ inline h2 pkrtz(float a, float b) {
  return __builtin_bit_cast(h2, __builtin_amdgcn_cvt_pkrtz(a, b));
}

#if defined(__has_builtin)
#if __has_builtin(__builtin_amdgcn_fdot2)
#define FDOT2(a, b, c) __builtin_amdgcn_fdot2((a), (b), (c), false)
#endif
#endif
#ifndef FDOT2
static __device__ inline float fdot2_fb(h2 a, h2 b, float c) {
  return fmaf((float)a.x, (float)b.x, fmaf((float)a.y, (float)b.y, c));
}
#define FDOT2(a, b, c) fdot2_fb((a), (b), (c))
#endif

// Full-wave max via DPP (VALU pipe only — off the LDS queue).
static __device__ inline float wave_max_dpp(float x) {
  int v = __float_as_int(x);
#define DPP_STEP(ctrl)                                                  \
  {                                                                     \
    int t = __builtin_amdgcn_update_dpp(v, v, (ctrl), 0xf, 0xf, false); \
    x = fmaxf(x, __int_as_float(t));                                    \
    v = __float_as_int(x);                                              \
  }
  DPP_STEP(0x111) DPP_STEP(0x112) DPP_STEP(0x114) DPP_STEP(0x118)
  DPP_STEP(0x142) DPP_STEP(0x143)
#undef DPP_STEP
  return __int_as_float(__builtin_amdgcn_readlane(v, 63));
}

static __device__ inline h2 bch2(unsigned u) { return __builtin_bit_cast(h2, u); }
static __device__ inline unsigned expbits(unsigned u) {
  return __float_as_uint(__expf(__uint_as_float(u)));
}

// Round-0 structure (2 independent chain waves + 2 stager waves, barrier
// only per 16-step chunk). Two changes vs round 0:
//  1. The per-step state broadcast is done with TRANSIENT v_readlane
//     inside the dot loop (state pair (2q,2q+1) = readlane(pk, q) feeds
//     its two dots immediately; one live broadcast value at a time, so
//     register pressure == round 0, unlike round 2's sst[64] which
//     evicted E into AGPRs). The chain issues ZERO LDS state ops — no
//     ds_write -> lgkmcnt -> 16x ds_read round trip on the carried
//     dependence.
//  2. exp() of emissions folded at staging time (bit-identical f32,
//     verified rounds 1-2), removing 2 transcendentals per fwd step.
__global__ __launch_bounds__(256)
__attribute__((amdgpu_waves_per_eu(1, 1)))
void crf_fb_kernel(const float* __restrict__ inputs,
                   const float* __restrict__ trans,
                   const float* __restrict__ start_t,
                   const float* __restrict__ end_t,
                   const int* __restrict__ tags,
                   const int* __restrict__ mask,
                   float* __restrict__ diff) {
  const int b = blockIdx.x;
  const int tid = threadIdx.x;
  const int lane = tid & 63;
  const int wid = tid >> 6;

  __shared__ __align__(16) float fbuf[2][CH * TT];  // fwd emissions, exp-folded
  __shared__ __align__(16) float bbuf[2][CH * TT];  // bwd emissions, exp-folded
  __shared__ __align__(16) h2 g_lds[64];            // bwd final state (epilogue)
  __shared__ float numA_sh, numB_sh;
  __shared__ int sb_sh;

  // ---- each wave computes len ----
  int lm = 0;
  const int* mk = mask + b * LL;
#pragma unroll
  for (int q = 0; q < LL / 64; ++q) lm += mk[q * 64 + lane];
#pragma unroll
  for (int d = 1; d < 64; d <<= 1) lm += __shfl_xor(lm, d);
  const int len = lm;            // [256, 512]
  const int m = (len - 1) >> 1;  // meeting point; m >= 127
  const int NC = (len - 1 - m + CH - 1) / CH;  // chunks (bwd has max steps)

  const float* erow = inputs + (size_t)b * LL * TT;
  const float2* er2 = (const float2*)erow;
  const float2* tr2 = (const float2*)trans;

  // stage 16 rows (8 KB), folding exp() so the chain never computes it
  auto STAGE = [&](float* dst, const float* gbase) {
    const uint4* gs = (const uint4*)gbase;
    uint4* ds = (uint4*)dst;
    uint4 v[8];
#pragma unroll
    for (int q = 0; q < 8; ++q) v[q] = gs[q * 64 + lane];
#pragma unroll
    for (int q = 0; q < 8; ++q) {
      uint4 o;
      o.x = expbits(v[q].x);
      o.y = expbits(v[q].y);
      o.z = expbits(v[q].z);
      o.w = expbits(v[q].w);
      ds[q * 64 + lane] = o;
    }
  };

  int S = 0;
  float inv_sc = 1.0f;
  int cur_ex = 0;
  h2 Ea0[64], Ea1[64];  // E fragments (fwd: col-pairs; bwd: row-pairs)
  h2 pk;                // this lane's state pair (states 2*lane, 2*lane+1)

  // ================= prologue =================
  if (wid == 0) {
#pragma unroll
    for (int p = 0; p < 64; ++p) {
      float2 r0 = tr2[(2 * p) * 64 + lane];      // row 2p, cols j0,j1
      float2 r1 = tr2[(2 * p + 1) * 64 + lane];  // row 2p+1
      h2 c0, c1;
      c0.x = (_Float16)__expf(r0.x);
      c0.y = (_Float16)__expf(r1.x);
      c1.x = (_Float16)__expf(r0.y);
      c1.y = (_Float16)__expf(r1.y);
      Ea0[p] = c0;
      Ea1[p] = c1;
    }
    float2 em0 = er2[lane];
    float f0 = __expf(start_t[2 * lane] + em0.x);
    float f1 = __expf(start_t[2 * lane + 1] + em0.y);
    pk = pkrtz(f0, f1);
    float mx = wave_max_dpp(fmaxf(f0, f1));
    int exm = (int)((__float_as_uint(mx) >> 23) & 255) - 127;
    inv_sc = __uint_as_float((unsigned)(120 - exm) << 23);
    cur_ex = exm + 7;
  } else if (wid == 1) {
#pragma unroll
    for (int p = 0; p < 64; ++p) {
      float2 r0 = tr2[(2 * lane) * 64 + p];
      float2 r1 = tr2[(2 * lane + 1) * 64 + p];
      h2 c0, c1;
      c0.x = (_Float16)__expf(r0.x);
      c0.y = (_Float16)__expf(r0.y);
      c1.x = (_Float16)__expf(r1.x);
      c1.y = (_Float16)__expf(r1.y);
      Ea0[p] = c0;
      Ea1[p] = c1;
    }
    float2 em = er2[(size_t)(len - 1) * 64 + lane];
    float g0 = __expf(end_t[2 * lane] + em.x);
    float g1 = __expf(end_t[2 * lane + 1] + em.y);
    pk = pkrtz(g0, g1);
    float mx = wave_max_dpp(fmaxf(g0, g1));
    int exm = (int)((__float_as_uint(mx) >> 23) & 255) - 127;
    inv_sc = __uint_as_float((unsigned)(120 - exm) << 23);
    cur_ex = exm + 7;
  } else if (wid == 2) {
    STAGE(fbuf[0], erow + 1 * TT);  // fwd chunk 0: rows 1..16
    // numerator half A: t in [0, len/2)
    const int* tg = tags + (size_t)b * LL;
    const int hl = len >> 1;
    float sc = 0.f;
    for (int t = lane; t < hl; t += 64) {
      int cu = tg[t];
      sc += erow[(size_t)t * TT + cu];
      if (t >= 1) sc += trans[tg[t - 1] * TT + cu];
    }
    if (lane == 0) sc += start_t[tg[0]];
#pragma unroll
    for (int d = 1; d < 64; d <<= 1) sc += __shfl_xor(sc, d);
    if (lane == 0) numA_sh = sc;
  } else {
    STAGE(bbuf[0], erow + (size_t)(len - 1 - CH) * TT);  // bwd chunk 0
    // numerator half B: t in [len/2, len)
    const int* tg = tags + (size_t)b * LL;
    const int hl = len >> 1;
    float sc = 0.f;
    for (int t = hl + lane; t < len; t += 64) {
      int cu = tg[t];
      sc += erow[(size_t)t * TT + cu];
      sc += trans[tg[t - 1] * TT + cu];
    }
    if (lane == 0) sc += end_t[tg[len - 1]];
#pragma unroll
    for (int d = 1; d < 64; d <<= 1) sc += __shfl_xor(sc, d);
    if (lane == 0) numB_sh = sc;
  }

  __syncthreads();

  // ================= chunk loop =================
  for (int c = 0; c < NC; ++c) {
    if (wid == 0) {
      // ---- forward chain steps of chunk c ----
      const float2* emb = (const float2*)fbuf[c & 1];
      const int tbeg = 1 + CH * c;
      const int tend = min(tbeg + CH - 1, m);
#pragma unroll 1
      for (int t = tbeg; t <= tend; ++t) {
        float2 fe = emb[(t - tbeg) * 64 + lane];  // exp already folded
        float f0 = fe.x * inv_sc;
        float f1 = fe.y * inv_sc;
        float a0 = 0.f, a1 = 0.f, a2 = 0.f, a3 = 0.f;
        float c0 = 0.f, c1 = 0.f, c2 = 0.f, c3 = 0.f;
        const int pki = (int)__builtin_bit_cast(unsigned, pk);
#pragma unroll
        for (int q = 0; q < 16; ++q) {
          // transient broadcasts: one live value per pair of dots
          h2 s0 = bch2((unsigned)__builtin_amdgcn_readlane(pki, 4 * q + 0));
          a0 = FDOT2(s0, Ea0[4 * q + 0], a0);
          c0 = FDOT2(s0, Ea1[4 * q + 0], c0);
          h2 s1 = bch2((unsigned)__builtin_amdgcn_readlane(pki, 4 * q + 1));
          a1 = FDOT2(s1, Ea0[4 * q + 1], a1);
          c1 = FDOT2(s1, Ea1[4 * q + 1], c1);
          h2 s2 = bch2((unsigned)__builtin_amdgcn_readlane(pki, 4 * q + 2));
          a2 = FDOT2(s2, Ea0[4 * q + 2], a2);
          c2 = FDOT2(s2, Ea1[4 * q + 2], c2);
          h2 s3 = bch2((unsigned)__builtin_amdgcn_readlane(pki, 4 * q + 3));
          a3 = FDOT2(s3, Ea0[4 * q + 3], a3);
          c3 = FDOT2(s3, Ea1[4 * q + 3], c3);
        }
        float w0 = ((a0 + a1) + (a2 + a3)) * f0;
        float w1 = ((c0 + c1) + (c2 + c3)) * f1;
        pk = pkrtz(w0, w1);
        S += cur_ex;
        float mx = wave_max_dpp(fmaxf(w0, w1));
        int exm = (int)((__float_as_uint(mx) >> 23) & 255) - 127;
        inv_sc = __uint_as_float((unsigned)(120 - exm) << 23);
        cur_ex = exm + 7;
      }
    } else if (wid == 1) {
      // ---- backward chain steps of chunk c ----
      const int thi = len - 2 - CH * c;
      const int lb = len - 1 - CH * (c + 1);  // staged base row
      const int tlo = max(m, lb);
      const float2* emb = (const float2*)bbuf[c & 1];
#pragma unroll 1
      for (int t = thi; t >= tlo; --t) {
        float2 pe = emb[(t - lb) * 64 + lane];  // exp already folded
        float a0 = 0.f, a1 = 0.f, a2 = 0.f, a3 = 0.f;
        float c0 = 0.f, c1 = 0.f, c2 = 0.f, c3 = 0.f;
        const int pki = (int)__builtin_bit_cast(unsigned, pk);
#pragma unroll
        for (int q = 0; q < 16; ++q) {
          h2 s0 = bch2((unsigned)__builtin_amdgcn_readlane(pki, 4 * q + 0));
          a0 = FDOT2(s0, Ea0[4 * q + 0], a0);
          c0 = FDOT2(s0, Ea1[4 * q + 0], c0);
          h2 s1 = bch2((unsigned)__builtin_amdgcn_readlane(pki, 4 * q + 1));
          a1 = FDOT2(s1, Ea0[4 * q + 1], a1);
          c1 = FDOT2(s1, Ea1[4 * q + 1], c1);
          h2 s2 = bch2((unsigned)__builtin_amdgcn_readlane(pki, 4 * q + 2));
          a2 = FDOT2(s2, Ea0[4 * q + 2], a2);
          c2 = FDOT2(s2, Ea1[4 * q + 2], c2);
          h2 s3 = bch2((unsigned)__builtin_amdgcn_readlane(pki, 4 * q + 3));
          a3 = FDOT2(s3, Ea0[4 * q + 3], a3);
          c3 = FDOT2(s3, Ea1[4 * q + 3], c3);
        }
        float v0 = (a0 + a1) + (a2 + a3);
        float v1 = (c0 + c1) + (c2 + c3);
        if (t > m) {  // fold exp(emit_t); at t==m store raw
          v0 *= pe.x;
          v1 *= pe.y;
        }
        float w0 = v0 * inv_sc, w1 = v1 * inv_sc;
        pk = pkrtz(w0, w1);
        S += cur_ex;
        float mx = wave_max_dpp(fmaxf(w0, w1));
        int exm = (int)((__float_as_uint(mx) >> 23) & 255) - 127;
        inv_sc = __uint_as_float((unsigned)(120 - exm) << 23);
        cur_ex = exm + 7;
      }
    } else if (wid == 2) {
      if (c + 1 < NC) STAGE(fbuf[(c + 1) & 1], erow + (size_t)(1 + CH * (c + 1)) * TT);
    } else {
      if (c + 1 < NC) STAGE(bbuf[(c + 1) & 1], erow + (size_t)(len - 1 - CH * (c + 2)) * TT);
    }
    __syncthreads();
  }

  if (wid == 1) {
    g_lds[lane] = pk;
    if (lane == 0) sb_sh = S;
  }
  __syncthreads();

  if (wid == 0) {
    h2 a = pk;  // final fwd state lives in this wave's registers
    h2 g = g_lds[lane];
    float v = (float)a.x * (float)g.x + (float)a.y * (float)g.y;
#pragma unroll
    for (int d = 1; d < 64; d <<= 1) v += __shfl_xor(v, d);
    if (lane == 0) {
      float log_den = (float)(S + sb_sh) * 0.6931471805599453f + __logf(v);
      diff[b] = (numA_sh + numB_sh) - log_den;
    }
  }
}

// Deterministic final reduction over batch.
__global__ void crf_sum_kernel(const float* __restrict__ diff,
                               float* __restrict__ out) {
  const int tid = threadIdx.x;  // 256
  float v = diff[tid];
#pragma unroll
  for (int d = 1; d < 64; d <<= 1) v += __shfl_xor(v, d);
  __shared__ float r[4];
  if ((tid & 63) == 0) r[tid >> 6] = v;
  __syncthreads();
  if (tid == 0) out[0] = r[0] + r[1] + r[2] + r[3];
}

extern "C" void kernel_launch(void* const* d_in, const int* in_sizes, int n_in,
                              void* d_out, int out_size, void* d_ws, size_t ws_size,
                              hipStream_t stream) {
  const float* inputs = (const float*)d_in[0];
  const float* trans = (const float*)d_in[1];
  const float* start_t = (const float*)d_in[2];
  const float* end_t = (const float*)d_in[3];
  const int* tags = (const int*)d_in[4];
  const int* mask = (const int*)d_in[5];
  float* diff = (float*)d_ws;  // 256 floats
  float* out = (float*)d_out;

  crf_fb_kernel<<<BB, 256, 0, stream>>>(inputs, trans, start_t, end_t, tags,
                                        mask, diff);
  crf_sum_kernel<<<1, 256, 0, stream>>>(diff, out);
}